// Round 1
// baseline (611.689 us; speedup 1.0000x reference)
//
#include <hip/hip_runtime.h>
#include <hip/hip_bf16.h>
#include <stdint.h>
#include <stddef.h>

// MoDE: top-2 of 8 experts, expert 7 = noop (identity * weight), cap = 1024.
// Tokens = 8192, H = 1024, I = 4096, 7 real experts.

#define N_TOK   8192
#define HDIM    1024
#define IDIM    4096
#define NEXP    7
#define CAP     1024

typedef __bf16 bf16_t;
typedef bf16_t bf16x8 __attribute__((ext_vector_type(8)));
typedef float  f32x4  __attribute__((ext_vector_type(4)));

typedef __attribute__((address_space(3))) char lds_char_t;
typedef __attribute__((address_space(1))) const char glob_char_t;

__device__ __forceinline__ void load_lds16(const void* g, void* l) {
    __builtin_amdgcn_global_load_lds((glob_char_t*)(uintptr_t)g,
                                     (lds_char_t*)(uintptr_t)l, 16, 0, 0);
}

__device__ __forceinline__ bf16x8 pack8(const float* v) {
    bf16x8 r;
#pragma unroll
    for (int j = 0; j < 8; j++) r[j] = (bf16_t)v[j];
    return r;
}

// ---------------- Router: logits -> softmax -> top2 -> per-token weights ----
// routew[t][0..6] = expert weight if selected else 0; routew[t][7] = noop coef.
__global__ __launch_bounds__(256) void router_kernel(
    const float* __restrict__ x, const float* __restrict__ rw,
    const float* __restrict__ rb, float* __restrict__ routew)
{
    const int wave = threadIdx.x >> 6, lane = threadIdx.x & 63;
    const int t = blockIdx.x * 4 + wave;
    const float4* xr = (const float4*)(x + (size_t)t * HDIM);
    float4 xv[4];
#pragma unroll
    for (int r = 0; r < 4; r++) xv[r] = xr[lane + r * 64];
    float p[8];
#pragma unroll
    for (int e = 0; e < 8; e++) {
        const float4* wr = (const float4*)(rw + (size_t)e * HDIM);
        float s = 0.f;
#pragma unroll
        for (int r = 0; r < 4; r++) {
            float4 wv = wr[lane + r * 64];
            s += xv[r].x * wv.x + xv[r].y * wv.y + xv[r].z * wv.z + xv[r].w * wv.w;
        }
#pragma unroll
        for (int o = 32; o; o >>= 1) s += __shfl_xor(s, o, 64);
        p[e] = s + rb[e];
    }
    // softmax over 8
    float m = p[0];
#pragma unroll
    for (int e = 1; e < 8; e++) m = fmaxf(m, p[e]);
    float sum = 0.f;
#pragma unroll
    for (int e = 0; e < 8; e++) { p[e] = expf(p[e] - m); sum += p[e]; }
    float inv = 1.f / sum;
#pragma unroll
    for (int e = 0; e < 8; e++) p[e] *= inv;
    // top-2 (ties -> lowest index, matching lax.top_k)
    int i1 = 0;
#pragma unroll
    for (int e = 1; e < 8; e++) if (p[e] > p[i1]) i1 = e;
    int i2 = (i1 == 0) ? 1 : 0;
#pragma unroll
    for (int e = 0; e < 8; e++) if (e != i1 && p[e] > p[i2]) i2 = e;
    if (lane == 0) {
#pragma unroll
        for (int c = 0; c < 8; c++)
            routew[(size_t)t * 8 + c] = (c == i1) ? p[i1] : ((c == i2) ? p[i2] : 0.f);
    }
}

// ---------------- Stable per-expert compaction with capacity ---------------
__global__ __launch_bounds__(1024) void compact_kernel(
    const float* __restrict__ routew, int* __restrict__ list,
    float* __restrict__ wsel)
{
    const int tid = threadIdx.x, wave = tid >> 6, lane = tid & 63;
    for (int i = tid; i < NEXP * CAP; i += 1024) { list[i] = -1; wsel[i] = 0.f; }
    __syncthreads();
    __shared__ int cnt[16][NEXP];
    int base[NEXP];
#pragma unroll
    for (int e = 0; e < NEXP; e++) base[e] = 0;
    const unsigned long long below = (lane == 63) ? ~0ull >> 1 : ((1ull << lane) - 1);
    for (int chunk = 0; chunk < N_TOK / 1024; chunk++) {
        const int t = chunk * 1024 + tid;
        float w[NEXP]; bool sel[NEXP]; int rnk[NEXP]; int wtot[NEXP];
#pragma unroll
        for (int e = 0; e < NEXP; e++) {
            w[e] = routew[(size_t)t * 8 + e];
            sel[e] = (w[e] > 0.f);
            unsigned long long mask = __ballot(sel[e]);
            rnk[e] = __popcll(mask & below);
            wtot[e] = __popcll(mask);
        }
        if (lane == 0) {
#pragma unroll
            for (int e = 0; e < NEXP; e++) cnt[wave][e] = wtot[e];
        }
        __syncthreads();
#pragma unroll
        for (int e = 0; e < NEXP; e++) {
            int pre = base[e];
            for (int w2 = 0; w2 < wave; w2++) pre += cnt[w2][e];
            int rank = pre + rnk[e];
            if (sel[e] && rank < CAP) {
                list[e * CAP + rank] = t;
                wsel[e * CAP + rank] = w[e];
            }
            int tot = 0;
            for (int w2 = 0; w2 < 16; w2++) tot += cnt[w2][e];
            base[e] += tot;
        }
        __syncthreads();
    }
}

// ---------------- Gather selected rows of x into bf16 A --------------------
__global__ __launch_bounds__(128) void gather_kernel(
    const float* __restrict__ x, const int* __restrict__ list,
    bf16_t* __restrict__ A)
{
    const int row = blockIdx.x;   // e*CAP + slot
    const int t = list[row];
    const int i = threadIdx.x;    // 128 threads * 8 elems
    float4 v0 = {0.f, 0.f, 0.f, 0.f}, v1 = v0;
    if (t >= 0) {
        const float4* xs = (const float4*)(x + (size_t)t * HDIM);
        v0 = xs[i * 2];
        v1 = xs[i * 2 + 1];
    }
    bf16x8 o;
    o[0] = (bf16_t)v0.x; o[1] = (bf16_t)v0.y; o[2] = (bf16_t)v0.z; o[3] = (bf16_t)v0.w;
    o[4] = (bf16_t)v1.x; o[5] = (bf16_t)v1.y; o[6] = (bf16_t)v1.z; o[7] = (bf16_t)v1.w;
    ((bf16x8*)(A + (size_t)row * HDIM))[i] = o;
}

// ---------------- Init output with noop (identity) expert ------------------
__global__ __launch_bounds__(256) void initout_kernel(
    const float* __restrict__ x, const float* __restrict__ routew,
    float* __restrict__ out)
{
    const int t = blockIdx.x;
    const float c = routew[(size_t)t * 8 + 7];
    const float4* xs = (const float4*)(x + (size_t)t * HDIM);
    float4* o = (float4*)(out + (size_t)t * HDIM);
    float4 v = xs[threadIdx.x];
    v.x *= c; v.y *= c; v.z *= c; v.w *= c;
    o[threadIdx.x] = v;
}

// ---------------- Grouped GEMM (bf16 MFMA 16x16x32, 128x128x32 tiles) ------
// A: [NEXP][CAP][KDIM] bf16 row-major (k-contig).
// W: [NEXP][KDIM][NDIM] fp32 (k-major) -> transposed+converted during staging.
// IS_G1: C = relu(A@W) stored bf16 to Hout.
// else : C = (A@W) * wsel[row], atomicAdd-scattered to out[token].
template<int KDIM, int NDIM, bool IS_G1>
__global__ __launch_bounds__(256) void ffn_gemm(
    const bf16_t* __restrict__ Ab, const float* __restrict__ Wb,
    bf16_t* __restrict__ Hout, const int* __restrict__ list,
    const float* __restrict__ wsel, float* __restrict__ out)
{
    constexpr int BM = 128, BN = 128, BK = 32;
    __shared__ __align__(16) bf16_t As[BM * BK];   // [m][k]
    __shared__ __align__(16) bf16_t Bs[BN * BK];   // [n][k], 16B-chunk XOR swizzled
    const int tid = threadIdx.x, wave = tid >> 6, lane = tid & 63;
    const int e = blockIdx.z, mblk = blockIdx.y * BM, nblk = blockIdx.x * BN;

    const bf16_t* Ae = Ab + ((size_t)e * CAP + mblk) * KDIM;
    const float*  We = Wb + (size_t)e * KDIM * NDIM + nblk;

    // A staging (global_load_lds, 16B/lane): 2 issues cover 128 rows x 32 k
    const int ar = tid >> 2, ac = (tid & 3) * 8;
    const bf16_t* ag0 = Ae + (size_t)ar * KDIM + ac;
    const bf16_t* ag1 = ag0 + (size_t)64 * KDIM;
    bf16_t* as0 = As + wave * 512;          // wave-uniform base (lane*16B implicit)
    bf16_t* as1 = As + 2048 + wave * 512;

    // B staging: thread handles n=bn, k-chunks {bc, bc+1} (8 k each)
    const int bn = tid & 127, bc = (tid >> 7) * 2;
    const float* bg = We + bn;
    bf16_t* bsw0 = Bs + bn * BK + ((bc ^ (bn & 3)) * 8);
    bf16_t* bsw1 = Bs + bn * BK + (((bc + 1) ^ (bn & 3)) * 8);

    // compute-phase fragment addresses
    const int wm = (wave & 1) * 64, wn = (wave >> 1) * 64;
    const int lr = lane & 15, q = lane >> 4;
    const int sw = q ^ ((wn + lr) & 3);

    f32x4 acc[4][4] = {};

    for (int k0 = 0; k0 < KDIM; k0 += BK) {
        load_lds16(ag0 + k0, as0);
        load_lds16(ag1 + k0, as1);
        const float* bp = bg + (size_t)(k0 + bc * 8) * NDIM;
        float v[16];
#pragma unroll
        for (int j = 0; j < 16; j++) v[j] = bp[(size_t)j * NDIM];
        bf16x8 p0 = pack8(v), p1 = pack8(v + 8);
        *(bf16x8*)bsw0 = p0;
        *(bf16x8*)bsw1 = p1;
        __syncthreads();
        bf16x8 af[4], bfr[4];
#pragma unroll
        for (int i = 0; i < 4; i++)
            af[i] = *(const bf16x8*)(As + (wm + i * 16 + lr) * BK + q * 8);
#pragma unroll
        for (int j = 0; j < 4; j++)
            bfr[j] = *(const bf16x8*)(Bs + (wn + j * 16 + lr) * BK + sw * 8);
#pragma unroll
        for (int i = 0; i < 4; i++)
#pragma unroll
            for (int j = 0; j < 4; j++)
                acc[i][j] = __builtin_amdgcn_mfma_f32_16x16x32_bf16(af[i], bfr[j], acc[i][j], 0, 0, 0);
        __syncthreads();
    }

    // Epilogue. C/D layout: col = lane&15, row = (lane>>4)*4 + reg.
    if (IS_G1) {
        bf16_t* Ho = Hout + ((size_t)e * CAP + mblk) * NDIM + nblk;
#pragma unroll
        for (int i = 0; i < 4; i++) {
            const int r0 = wm + i * 16 + q * 4;
#pragma unroll
            for (int reg = 0; reg < 4; reg++) {
                bf16_t* row = Ho + (size_t)(r0 + reg) * NDIM;
#pragma unroll
                for (int j = 0; j < 4; j++)
                    row[wn + j * 16 + lr] = (bf16_t)fmaxf(acc[i][j][reg], 0.f);
            }
        }
    } else {
#pragma unroll
        for (int i = 0; i < 4; i++) {
            const int r0 = mblk + wm + i * 16 + q * 4;
#pragma unroll
            for (int reg = 0; reg < 4; reg++) {
                const int row = r0 + reg;
                const int tok = list[e * CAP + row];
                const float wgt = wsel[e * CAP + row];
                if (tok >= 0) {
                    float* orow = out + (size_t)tok * NDIM + nblk;
#pragma unroll
                    for (int j = 0; j < 4; j++)
                        atomicAdd(orow + wn + j * 16 + lr, acc[i][j][reg] * wgt);
                }
            }
        }
    }
}

// ---------------- Launch ---------------------------------------------------
extern "C" void kernel_launch(void* const* d_in, const int* in_sizes, int n_in,
                              void* d_out, int out_size, void* d_ws, size_t ws_size,
                              hipStream_t stream) {
    const float* x  = (const float*)d_in[0];
    const float* rw = (const float*)d_in[1];
    const float* rb = (const float*)d_in[2];
    const float* w1 = (const float*)d_in[3];   // [7][1024][4096]
    const float* w2 = (const float*)d_in[4];   // [7][4096][1024]
    float* out = (float*)d_out;

    char* ws = (char*)d_ws;
    // ws layout (bytes):
    //   routew: 8192*8*4      = 262144
    //   list:   7*1024*4     = 28672
    //   wsel:   7*1024*4     = 28672
    //   A:      7*1024*1024*2 = 14680064  (bf16)
    //   h:      7*1024*4096*2 = 58720256  (bf16)
    float*  routew = (float*)(ws);
    int*    list   = (int*)(ws + 262144);
    float*  wsel   = (float*)(ws + 262144 + 28672);
    bf16_t* Abuf   = (bf16_t*)(ws + 319488);
    bf16_t* Hbuf   = (bf16_t*)(ws + 319488 + 14680064);

    router_kernel<<<N_TOK / 4, 256, 0, stream>>>(x, rw, rb, routew);
    compact_kernel<<<1, 1024, 0, stream>>>(routew, list, wsel);
    gather_kernel<<<NEXP * CAP, 128, 0, stream>>>(x, list, Abuf);
    initout_kernel<<<N_TOK, 256, 0, stream>>>(x, routew, out);
    ffn_gemm<HDIM, IDIM, true><<<dim3(IDIM / 128, CAP / 128, NEXP), 256, 0, stream>>>(
        Abuf, w1, Hbuf, nullptr, nullptr, nullptr);
    ffn_gemm<IDIM, HDIM, false><<<dim3(HDIM / 128, CAP / 128, NEXP), 256, 0, stream>>>(
        Hbuf, w2, nullptr, list, wsel, out);
}

// Round 2
// 551.713 us; speedup vs baseline: 1.1087x; 1.1087x over previous
//
#include <hip/hip_runtime.h>
#include <hip/hip_bf16.h>
#include <stdint.h>
#include <stddef.h>

// MoDE: top-2 of 8 experts, expert 7 = noop (identity * weight), cap = 1024.
// Tokens = 8192, H = 1024, I = 4096, 7 real experts.

#define N_TOK   8192
#define HDIM    1024
#define IDIM    4096
#define NEXP    7
#define CAP     1024

typedef __bf16 bf16_t;
typedef bf16_t bf16x8 __attribute__((ext_vector_type(8)));
typedef float  f32x4  __attribute__((ext_vector_type(4)));

typedef __attribute__((address_space(3))) char lds_char_t;
typedef __attribute__((address_space(1))) const char glob_char_t;

__device__ __forceinline__ void load_lds16(const void* g, void* l) {
    __builtin_amdgcn_global_load_lds((glob_char_t*)(uintptr_t)g,
                                     (lds_char_t*)(uintptr_t)l, 16, 0, 0);
}

__device__ __forceinline__ bf16x8 pack8(const float* v) {
    bf16x8 r;
#pragma unroll
    for (int j = 0; j < 8; j++) r[j] = (bf16_t)v[j];
    return r;
}

// ---------------- Router: logits -> softmax -> top2 -> per-token weights ----
__global__ __launch_bounds__(256) void router_kernel(
    const float* __restrict__ x, const float* __restrict__ rw,
    const float* __restrict__ rb, float* __restrict__ routew)
{
    const int wave = threadIdx.x >> 6, lane = threadIdx.x & 63;
    const int t = blockIdx.x * 4 + wave;
    const float4* xr = (const float4*)(x + (size_t)t * HDIM);
    float4 xv[4];
#pragma unroll
    for (int r = 0; r < 4; r++) xv[r] = xr[lane + r * 64];
    float p[8];
#pragma unroll
    for (int e = 0; e < 8; e++) {
        const float4* wr = (const float4*)(rw + (size_t)e * HDIM);
        float s = 0.f;
#pragma unroll
        for (int r = 0; r < 4; r++) {
            float4 wv = wr[lane + r * 64];
            s += xv[r].x * wv.x + xv[r].y * wv.y + xv[r].z * wv.z + xv[r].w * wv.w;
        }
#pragma unroll
        for (int o = 32; o; o >>= 1) s += __shfl_xor(s, o, 64);
        p[e] = s + rb[e];
    }
    float m = p[0];
#pragma unroll
    for (int e = 1; e < 8; e++) m = fmaxf(m, p[e]);
    float sum = 0.f;
#pragma unroll
    for (int e = 0; e < 8; e++) { p[e] = expf(p[e] - m); sum += p[e]; }
    float inv = 1.f / sum;
#pragma unroll
    for (int e = 0; e < 8; e++) p[e] *= inv;
    int i1 = 0;
#pragma unroll
    for (int e = 1; e < 8; e++) if (p[e] > p[i1]) i1 = e;
    int i2 = (i1 == 0) ? 1 : 0;
#pragma unroll
    for (int e = 0; e < 8; e++) if (e != i1 && p[e] > p[i2]) i2 = e;
    if (lane == 0) {
#pragma unroll
        for (int c = 0; c < 8; c++)
            routew[(size_t)t * 8 + c] = (c == i1) ? p[i1] : ((c == i2) ? p[i2] : 0.f);
    }
}

// ---------------- Stable per-expert compaction (one block per expert) ------
__global__ __launch_bounds__(1024) void compact_kernel(
    const float* __restrict__ routew, int* __restrict__ list,
    float* __restrict__ wsel)
{
    const int e = blockIdx.x;
    const int tid = threadIdx.x, wave = tid >> 6, lane = tid & 63;
    for (int i = tid; i < CAP; i += 1024) { list[e * CAP + i] = -1; wsel[e * CAP + i] = 0.f; }
    __shared__ int cnt[16];
    __syncthreads();
    int base = 0;
    const unsigned long long below = (lane == 63) ? ~0ull >> 1 : ((1ull << lane) - 1);
    for (int chunk = 0; chunk < N_TOK / 1024; chunk++) {
        const int t = chunk * 1024 + tid;
        const float w = routew[(size_t)t * 8 + e];
        const bool sel = (w > 0.f);
        const unsigned long long mask = __ballot(sel);
        const int rnk = __popcll(mask & below);
        if (lane == 0) cnt[wave] = __popcll(mask);
        __syncthreads();
        int pre = base;
        for (int w2 = 0; w2 < wave; w2++) pre += cnt[w2];
        const int rank = pre + rnk;
        if (sel && rank < CAP) { list[e * CAP + rank] = t; wsel[e * CAP + rank] = w; }
        int tot = 0;
        for (int w2 = 0; w2 < 16; w2++) tot += cnt[w2];
        base += tot;
        __syncthreads();
    }
}

// ---------------- Gather selected rows of x into bf16 A --------------------
__global__ __launch_bounds__(128) void gather_kernel(
    const float* __restrict__ x, const int* __restrict__ list,
    bf16_t* __restrict__ A)
{
    const int row = blockIdx.x;   // e*CAP + slot
    const int t = list[row];
    const int i = threadIdx.x;    // 128 threads * 8 elems
    float4 v0 = {0.f, 0.f, 0.f, 0.f}, v1 = v0;
    if (t >= 0) {
        const float4* xs = (const float4*)(x + (size_t)t * HDIM);
        v0 = xs[i * 2];
        v1 = xs[i * 2 + 1];
    }
    bf16x8 o;
    o[0] = (bf16_t)v0.x; o[1] = (bf16_t)v0.y; o[2] = (bf16_t)v0.z; o[3] = (bf16_t)v0.w;
    o[4] = (bf16_t)v1.x; o[5] = (bf16_t)v1.y; o[6] = (bf16_t)v1.z; o[7] = (bf16_t)v1.w;
    ((bf16x8*)(A + (size_t)row * HDIM))[i] = o;
}

// ---------------- Init output with noop (identity) expert ------------------
__global__ __launch_bounds__(256) void initout_kernel(
    const float* __restrict__ x, const float* __restrict__ routew,
    float* __restrict__ out)
{
    const int t = blockIdx.x;
    const float c = routew[(size_t)t * 8 + 7];
    const float4* xs = (const float4*)(x + (size_t)t * HDIM);
    float4* o = (float4*)(out + (size_t)t * HDIM);
    float4 v = xs[threadIdx.x];
    v.x *= c; v.y *= c; v.z *= c; v.w *= c;
    o[threadIdx.x] = v;
}

// ---------------- Transpose + convert: W [e][K][N] f32 -> Wt [e][N][K] bf16 -
template<int K, int N>
__global__ __launch_bounds__(256) void transpose_cvt(
    const float* __restrict__ W, bf16_t* __restrict__ Wt)
{
    __shared__ float Ts[64][65];
    const int t = threadIdx.x;
    const int e = blockIdx.z;
    const int ktile = blockIdx.y * 64, ntile = blockIdx.x * 64;
    const float* We = W + (size_t)e * K * N;
    const int kr = t >> 4, nc = (t & 15) * 4;
#pragma unroll
    for (int j = 0; j < 4; j++) {
        const float4 v = *(const float4*)(We + (size_t)(ktile + kr + j * 16) * N + ntile + nc);
        Ts[nc + 0][kr + j * 16] = v.x;
        Ts[nc + 1][kr + j * 16] = v.y;
        Ts[nc + 2][kr + j * 16] = v.z;
        Ts[nc + 3][kr + j * 16] = v.w;
    }
    __syncthreads();
    const int n = t >> 2, kc = (t & 3) * 16;
    bf16_t* o = Wt + ((size_t)e * N + ntile + n) * K + ktile + kc;
    bf16x8 p0, p1;
#pragma unroll
    for (int i = 0; i < 8; i++) {
        p0[i] = (bf16_t)Ts[n][kc + i];
        p1[i] = (bf16_t)Ts[n][kc + 8 + i];
    }
    ((bf16x8*)o)[0] = p0;
    ((bf16x8*)o)[1] = p1;
}

// ---------------- m97-style GEMM: A[e][CAP][K] bf16, Bt[e][N][K] bf16 ------
// IS_G1: C = relu(A@B^T) -> bf16 Hout.  else: atomicAdd(out[tok], C*wsel).
template<int KDIM, int NDIM, int KSPLIT, bool IS_G1>
__global__ __launch_bounds__(256) void ffn_gemm_t(
    const bf16_t* __restrict__ Ab, const bf16_t* __restrict__ Bt,
    bf16_t* __restrict__ Hout, const int* __restrict__ list,
    const float* __restrict__ wsel, float* __restrict__ out)
{
    constexpr int BM = 128, BN = 128, BK = 32;
    constexpr int KLEN = KDIM / KSPLIT;
    __shared__ __align__(16) bf16_t As[BM * BK];
    __shared__ __align__(16) bf16_t Bs[BN * BK];
    const int tid = threadIdx.x, wave = tid >> 6;
    const int lane = tid & 63;
    const int e = blockIdx.z / KSPLIT, ks = blockIdx.z % KSPLIT;
    const int mblk = blockIdx.y * BM, nblk = blockIdx.x * BN;

    const bf16_t* Ae = Ab + ((size_t)e * CAP + mblk) * KDIM + (size_t)ks * KLEN;
    const bf16_t* Be = Bt + ((size_t)e * NDIM + nblk) * KDIM + (size_t)ks * KLEN;

    const int r = tid >> 2, c = (tid & 3) * 8;
    const bf16_t* ag0 = Ae + (size_t)r * KDIM + c;
    const bf16_t* ag1 = ag0 + (size_t)64 * KDIM;
    const bf16_t* bg0 = Be + (size_t)r * KDIM + c;
    const bf16_t* bg1 = bg0 + (size_t)64 * KDIM;
    bf16_t* as0 = As + wave * 512;          // wave-uniform base + lane*16B
    bf16_t* as1 = As + 2048 + wave * 512;
    bf16_t* bs0 = Bs + wave * 512;
    bf16_t* bs1 = Bs + 2048 + wave * 512;

    const int wm = (wave & 1) * 64, wn = (wave >> 1) * 64;
    const int lr = lane & 15, q = lane >> 4;

    f32x4 acc[4][4] = {};

    for (int k0 = 0; k0 < KLEN; k0 += BK) {
        load_lds16(ag0 + k0, as0);
        load_lds16(ag1 + k0, as1);
        load_lds16(bg0 + k0, bs0);
        load_lds16(bg1 + k0, bs1);
        __syncthreads();
        bf16x8 af[4], bfr[4];
#pragma unroll
        for (int i = 0; i < 4; i++)
            af[i] = *(const bf16x8*)(As + (wm + i * 16 + lr) * BK + q * 8);
#pragma unroll
        for (int j = 0; j < 4; j++)
            bfr[j] = *(const bf16x8*)(Bs + (wn + j * 16 + lr) * BK + q * 8);
#pragma unroll
        for (int i = 0; i < 4; i++)
#pragma unroll
            for (int j = 0; j < 4; j++)
                acc[i][j] = __builtin_amdgcn_mfma_f32_16x16x32_bf16(af[i], bfr[j], acc[i][j], 0, 0, 0);
        __syncthreads();
    }

    // C/D layout: col = lane&15, row = (lane>>4)*4 + reg.
    if (IS_G1) {
        bf16_t* Ho = Hout + ((size_t)e * CAP + mblk) * NDIM + nblk;
#pragma unroll
        for (int i = 0; i < 4; i++) {
            const int r0 = wm + i * 16 + q * 4;
#pragma unroll
            for (int reg = 0; reg < 4; reg++) {
                bf16_t* row = Ho + (size_t)(r0 + reg) * NDIM;
#pragma unroll
                for (int j = 0; j < 4; j++)
                    row[wn + j * 16 + lr] = (bf16_t)fmaxf(acc[i][j][reg], 0.f);
            }
        }
    } else {
#pragma unroll
        for (int i = 0; i < 4; i++) {
            const int r0 = mblk + wm + i * 16 + q * 4;
#pragma unroll
            for (int reg = 0; reg < 4; reg++) {
                const int row = r0 + reg;
                const int tok = list[e * CAP + row];
                const float wgt = wsel[e * CAP + row];
                if (tok >= 0) {
                    float* orow = out + (size_t)tok * NDIM + nblk;
#pragma unroll
                    for (int j = 0; j < 4; j++)
                        atomicAdd(orow + wn + j * 16 + lr, acc[i][j][reg] * wgt);
                }
            }
        }
    }
}

// ---------------- Fallback GEMM (round-1, fused fp32->bf16 B staging) ------
template<int KDIM, int NDIM, bool IS_G1>
__global__ __launch_bounds__(256) void ffn_gemm_fused(
    const bf16_t* __restrict__ Ab, const float* __restrict__ Wb,
    bf16_t* __restrict__ Hout, const int* __restrict__ list,
    const float* __restrict__ wsel, float* __restrict__ out)
{
    constexpr int BM = 128, BN = 128, BK = 32;
    __shared__ __align__(16) bf16_t As[BM * BK];
    __shared__ __align__(16) bf16_t Bs[BN * BK];
    const int tid = threadIdx.x, wave = tid >> 6, lane = tid & 63;
    const int e = blockIdx.z, mblk = blockIdx.y * BM, nblk = blockIdx.x * BN;

    const bf16_t* Ae = Ab + ((size_t)e * CAP + mblk) * KDIM;
    const float*  We = Wb + (size_t)e * KDIM * NDIM + nblk;

    const int ar = tid >> 2, ac = (tid & 3) * 8;
    const bf16_t* ag0 = Ae + (size_t)ar * KDIM + ac;
    const bf16_t* ag1 = ag0 + (size_t)64 * KDIM;
    bf16_t* as0 = As + wave * 512;
    bf16_t* as1 = As + 2048 + wave * 512;

    const int bn = tid & 127, bc = (tid >> 7) * 2;
    const float* bg = We + bn;
    bf16_t* bsw0 = Bs + bn * BK + ((bc ^ (bn & 3)) * 8);
    bf16_t* bsw1 = Bs + bn * BK + (((bc + 1) ^ (bn & 3)) * 8);

    const int wm = (wave & 1) * 64, wn = (wave >> 1) * 64;
    const int lr = lane & 15, q = lane >> 4;
    const int sw = q ^ ((wn + lr) & 3);

    f32x4 acc[4][4] = {};

    for (int k0 = 0; k0 < KDIM; k0 += BK) {
        load_lds16(ag0 + k0, as0);
        load_lds16(ag1 + k0, as1);
        const float* bp = bg + (size_t)(k0 + bc * 8) * NDIM;
        float v[16];
#pragma unroll
        for (int j = 0; j < 16; j++) v[j] = bp[(size_t)j * NDIM];
        bf16x8 p0 = pack8(v), p1 = pack8(v + 8);
        *(bf16x8*)bsw0 = p0;
        *(bf16x8*)bsw1 = p1;
        __syncthreads();
        bf16x8 af[4], bfr[4];
#pragma unroll
        for (int i = 0; i < 4; i++)
            af[i] = *(const bf16x8*)(As + (wm + i * 16 + lr) * BK + q * 8);
#pragma unroll
        for (int j = 0; j < 4; j++)
            bfr[j] = *(const bf16x8*)(Bs + (wn + j * 16 + lr) * BK + sw * 8);
#pragma unroll
        for (int i = 0; i < 4; i++)
#pragma unroll
            for (int j = 0; j < 4; j++)
                acc[i][j] = __builtin_amdgcn_mfma_f32_16x16x32_bf16(af[i], bfr[j], acc[i][j], 0, 0, 0);
        __syncthreads();
    }

    if (IS_G1) {
        bf16_t* Ho = Hout + ((size_t)e * CAP + mblk) * NDIM + nblk;
#pragma unroll
        for (int i = 0; i < 4; i++) {
            const int r0 = wm + i * 16 + q * 4;
#pragma unroll
            for (int reg = 0; reg < 4; reg++) {
                bf16_t* row = Ho + (size_t)(r0 + reg) * NDIM;
#pragma unroll
                for (int j = 0; j < 4; j++)
                    row[wn + j * 16 + lr] = (bf16_t)fmaxf(acc[i][j][reg], 0.f);
            }
        }
    } else {
#pragma unroll
        for (int i = 0; i < 4; i++) {
            const int r0 = mblk + wm + i * 16 + q * 4;
#pragma unroll
            for (int reg = 0; reg < 4; reg++) {
                const int row = r0 + reg;
                const int tok = list[e * CAP + row];
                const float wgt = wsel[e * CAP + row];
                if (tok >= 0) {
                    float* orow = out + (size_t)tok * NDIM + nblk;
#pragma unroll
                    for (int j = 0; j < 4; j++)
                        atomicAdd(orow + wn + j * 16 + lr, acc[i][j][reg] * wgt);
                }
            }
        }
    }
}

// ---------------- Launch ---------------------------------------------------
extern "C" void kernel_launch(void* const* d_in, const int* in_sizes, int n_in,
                              void* d_out, int out_size, void* d_ws, size_t ws_size,
                              hipStream_t stream) {
    const float* x  = (const float*)d_in[0];
    const float* rw = (const float*)d_in[1];
    const float* rb = (const float*)d_in[2];
    const float* w1 = (const float*)d_in[3];   // [7][1024][4096] f32
    const float* w2 = (const float*)d_in[4];   // [7][4096][1024] f32
    float* out = (float*)d_out;

    char* ws = (char*)d_ws;
    // ws layout:
    //   routew  @0        262144
    //   list    @262144   28672
    //   wsel    @290816   28672
    //   Abuf    @319488   14680064   (bf16 [7][1024][1024])
    //   Hbuf    @14999552 58720256   (bf16 [7][1024][4096])
    //   W1t/W2t @73719808 58720256   (bf16, W2t aliases W1t after GEMM1)
    float*  routew = (float*)(ws);
    int*    list   = (int*)(ws + 262144);
    float*  wsel   = (float*)(ws + 262144 + 28672);
    bf16_t* Abuf   = (bf16_t*)(ws + 319488);
    bf16_t* Hbuf   = (bf16_t*)(ws + 14999552);
    bf16_t* Wt     = (bf16_t*)(ws + 73719808);

    const size_t NEED = 73719808ull + 58720256ull;   // 132.4 MB

    router_kernel<<<N_TOK / 4, 256, 0, stream>>>(x, rw, rb, routew);
    compact_kernel<<<NEXP, 1024, 0, stream>>>(routew, list, wsel);
    gather_kernel<<<NEXP * CAP, 128, 0, stream>>>(x, list, Abuf);
    initout_kernel<<<N_TOK, 256, 0, stream>>>(x, routew, out);

    if (ws_size >= NEED) {
        // transpose w1 -> Wt, GEMM1, transpose w2 -> Wt (aliased), GEMM2
        transpose_cvt<HDIM, IDIM><<<dim3(IDIM / 64, HDIM / 64, NEXP), 256, 0, stream>>>(w1, Wt);
        ffn_gemm_t<HDIM, IDIM, 1, true><<<dim3(IDIM / 128, CAP / 128, NEXP), 256, 0, stream>>>(
            Abuf, Wt, Hbuf, nullptr, nullptr, nullptr);
        transpose_cvt<IDIM, HDIM><<<dim3(HDIM / 64, IDIM / 64, NEXP), 256, 0, stream>>>(w2, Wt);
        ffn_gemm_t<IDIM, HDIM, 2, false><<<dim3(HDIM / 128, CAP / 128, NEXP * 2), 256, 0, stream>>>(
            Hbuf, Wt, nullptr, list, wsel, out);
    } else {
        ffn_gemm_fused<HDIM, IDIM, true><<<dim3(IDIM / 128, CAP / 128, NEXP), 256, 0, stream>>>(
            Abuf, w1, Hbuf, nullptr, nullptr, nullptr);
        ffn_gemm_fused<IDIM, HDIM, false><<<dim3(HDIM / 128, CAP / 128, NEXP), 256, 0, stream>>>(
            Hbuf, w2, nullptr, list, wsel, out);
    }
}

// Round 3
// 492.825 us; speedup vs baseline: 1.2412x; 1.1195x over previous
//
#include <hip/hip_runtime.h>
#include <hip/hip_bf16.h>
#include <stdint.h>
#include <stddef.h>

// MoDE: top-2 of 8 experts, expert 7 = noop (identity * weight), cap = 1024.
// Tokens = 8192, H = 1024, I = 4096, 7 real experts.

#define N_TOK   8192
#define HDIM    1024
#define IDIM    4096
#define NEXP    7
#define CAP     1024

typedef __bf16 bf16_t;
typedef bf16_t bf16x8 __attribute__((ext_vector_type(8)));
typedef float  f32x4  __attribute__((ext_vector_type(4)));

typedef __attribute__((address_space(3))) char lds_char_t;
typedef __attribute__((address_space(1))) const char glob_char_t;

__device__ __forceinline__ void load_lds16(const void* g, void* l) {
    __builtin_amdgcn_global_load_lds((glob_char_t*)(uintptr_t)g,
                                     (lds_char_t*)(uintptr_t)l, 16, 0, 0);
}

__device__ __forceinline__ bf16x8 pack8(const float* v) {
    bf16x8 r;
#pragma unroll
    for (int j = 0; j < 8; j++) r[j] = (bf16_t)v[j];
    return r;
}

// ---------------- Router + noop-expert output init (fused) -----------------
// routew[t][0..6] = expert weight if selected else 0; routew[t][7] = noop coef.
// Also writes out[t] = x[t] * noop_coef (GEMM2 atomically adds expert terms).
__global__ __launch_bounds__(256) void router_kernel(
    const float* __restrict__ x, const float* __restrict__ rw,
    const float* __restrict__ rb, float* __restrict__ routew,
    float* __restrict__ out)
{
    const int wave = threadIdx.x >> 6, lane = threadIdx.x & 63;
    const int t = blockIdx.x * 4 + wave;
    const float4* xr = (const float4*)(x + (size_t)t * HDIM);
    float4 xv[4];
#pragma unroll
    for (int r = 0; r < 4; r++) xv[r] = xr[lane + r * 64];
    float p[8];
#pragma unroll
    for (int e = 0; e < 8; e++) {
        const float4* wr = (const float4*)(rw + (size_t)e * HDIM);
        float s = 0.f;
#pragma unroll
        for (int r = 0; r < 4; r++) {
            float4 wv = wr[lane + r * 64];
            s += xv[r].x * wv.x + xv[r].y * wv.y + xv[r].z * wv.z + xv[r].w * wv.w;
        }
#pragma unroll
        for (int o = 32; o; o >>= 1) s += __shfl_xor(s, o, 64);
        p[e] = s + rb[e];
    }
    float m = p[0];
#pragma unroll
    for (int e = 1; e < 8; e++) m = fmaxf(m, p[e]);
    float sum = 0.f;
#pragma unroll
    for (int e = 0; e < 8; e++) { p[e] = expf(p[e] - m); sum += p[e]; }
    float inv = 1.f / sum;
#pragma unroll
    for (int e = 0; e < 8; e++) p[e] *= inv;
    int i1 = 0;
#pragma unroll
    for (int e = 1; e < 8; e++) if (p[e] > p[i1]) i1 = e;
    int i2 = (i1 == 0) ? 1 : 0;
#pragma unroll
    for (int e = 0; e < 8; e++) if (e != i1 && p[e] > p[i2]) i2 = e;
    if (lane == 0) {
#pragma unroll
        for (int c = 0; c < 8; c++)
            routew[(size_t)t * 8 + c] = (c == i1) ? p[i1] : ((c == i2) ? p[i2] : 0.f);
    }
    const float c7 = (i1 == 7 || i2 == 7) ? p[7] : 0.f;
    float4* o = (float4*)(out + (size_t)t * HDIM);
#pragma unroll
    for (int r = 0; r < 4; r++) {
        float4 v = xv[r];
        v.x *= c7; v.y *= c7; v.z *= c7; v.w *= c7;
        o[lane + r * 64] = v;
    }
}

// ---------------- Stable per-expert compaction (one block per expert) ------
__global__ __launch_bounds__(1024) void compact_kernel(
    const float* __restrict__ routew, int* __restrict__ list,
    float* __restrict__ wsel)
{
    const int e = blockIdx.x;
    const int tid = threadIdx.x, wave = tid >> 6, lane = tid & 63;
    for (int i = tid; i < CAP; i += 1024) { list[e * CAP + i] = -1; wsel[e * CAP + i] = 0.f; }
    __shared__ int cnt[16];
    __syncthreads();
    int base = 0;
    const unsigned long long below = (lane == 63) ? ~0ull >> 1 : ((1ull << lane) - 1);
    for (int chunk = 0; chunk < N_TOK / 1024; chunk++) {
        const int t = chunk * 1024 + tid;
        const float w = routew[(size_t)t * 8 + e];
        const bool sel = (w > 0.f);
        const unsigned long long mask = __ballot(sel);
        const int rnk = __popcll(mask & below);
        if (lane == 0) cnt[wave] = __popcll(mask);
        __syncthreads();
        int pre = base;
        for (int w2 = 0; w2 < wave; w2++) pre += cnt[w2];
        const int rank = pre + rnk;
        if (sel && rank < CAP) { list[e * CAP + rank] = t; wsel[e * CAP + rank] = w; }
        int tot = 0;
        for (int w2 = 0; w2 < 16; w2++) tot += cnt[w2];
        base += tot;
        __syncthreads();
    }
}

// ---------------- Gather selected rows of x into bf16 A --------------------
__global__ __launch_bounds__(128) void gather_kernel(
    const float* __restrict__ x, const int* __restrict__ list,
    bf16_t* __restrict__ A)
{
    const int row = blockIdx.x;   // e*CAP + slot
    const int t = list[row];
    const int i = threadIdx.x;    // 128 threads * 8 elems
    float4 v0 = {0.f, 0.f, 0.f, 0.f}, v1 = v0;
    if (t >= 0) {
        const float4* xs = (const float4*)(x + (size_t)t * HDIM);
        v0 = xs[i * 2];
        v1 = xs[i * 2 + 1];
    }
    bf16x8 o;
    o[0] = (bf16_t)v0.x; o[1] = (bf16_t)v0.y; o[2] = (bf16_t)v0.z; o[3] = (bf16_t)v0.w;
    o[4] = (bf16_t)v1.x; o[5] = (bf16_t)v1.y; o[6] = (bf16_t)v1.z; o[7] = (bf16_t)v1.w;
    ((bf16x8*)(A + (size_t)row * HDIM))[i] = o;
}

// ---------------- Transpose + convert: W [e][K][N] f32 -> Wt [e][N][K] bf16 -
template<int K, int N>
__global__ __launch_bounds__(256) void transpose_cvt(
    const float* __restrict__ W, bf16_t* __restrict__ Wt)
{
    __shared__ float Ts[64][65];
    const int t = threadIdx.x;
    const int e = blockIdx.z;
    const int ktile = blockIdx.y * 64, ntile = blockIdx.x * 64;
    const float* We = W + (size_t)e * K * N;
    const int kr = t >> 4, nc = (t & 15) * 4;
#pragma unroll
    for (int j = 0; j < 4; j++) {
        const float4 v = *(const float4*)(We + (size_t)(ktile + kr + j * 16) * N + ntile + nc);
        Ts[nc + 0][kr + j * 16] = v.x;
        Ts[nc + 1][kr + j * 16] = v.y;
        Ts[nc + 2][kr + j * 16] = v.z;
        Ts[nc + 3][kr + j * 16] = v.w;
    }
    __syncthreads();
    const int n = t >> 2, kc = (t & 3) * 16;
    bf16_t* o = Wt + ((size_t)e * N + ntile + n) * K + ktile + kc;
    bf16x8 p0, p1;
#pragma unroll
    for (int i = 0; i < 8; i++) {
        p0[i] = (bf16_t)Ts[n][kc + i];
        p1[i] = (bf16_t)Ts[n][kc + 8 + i];
    }
    ((bf16x8*)o)[0] = p0;
    ((bf16x8*)o)[1] = p1;
}

// ---------------- Pipelined GEMM: A[e][CAP][K] bf16, Bt[e][N][K] bf16 ------
// Double-buffered LDS; prefetch next tile with raw s_barrier + vmcnt(4) so
// in-flight loads are never drained at the barrier (m139/AITER pattern).
// LDS 16B-chunk XOR swizzle (slot cc holds global chunk cc^((row>>1)&3))
// makes frag ds_read_b128 conflict-free while keeping DMA lane-contiguity.
// IS_G1: C = relu(A@B^T) -> bf16 Hout.  else: atomicAdd(out[tok], C*wsel).
template<int KDIM, int NDIM, int KSPLIT, bool IS_G1>
__global__ __launch_bounds__(256) void ffn_gemm_t(
    const bf16_t* __restrict__ Ab, const bf16_t* __restrict__ Bt,
    bf16_t* __restrict__ Hout, const int* __restrict__ list,
    const float* __restrict__ wsel, float* __restrict__ out)
{
    constexpr int BM = 128, BN = 128, BK = 32;
    constexpr int KLEN = KDIM / KSPLIT;
    __shared__ __align__(16) bf16_t As[2][BM * BK];
    __shared__ __align__(16) bf16_t Bs[2][BN * BK];
    const int tid = threadIdx.x, wave = tid >> 6, lane = tid & 63;
    const int e = blockIdx.z / KSPLIT, ks = blockIdx.z % KSPLIT;
    const int mblk = blockIdx.y * BM, nblk = blockIdx.x * BN;

    const bf16_t* Ae = Ab + ((size_t)e * CAP + mblk) * KDIM + (size_t)ks * KLEN;
    const bf16_t* Be = Bt + ((size_t)e * NDIM + nblk) * KDIM + (size_t)ks * KLEN;

    const int r = tid >> 2;                      // tile row 0..63 (issue 0)
    const int cc = tid & 3;                      // LDS 16B slot within row
    const int c = cc ^ ((r >> 1) & 3);           // swizzle: global chunk loaded
    const bf16_t* ag0 = Ae + (size_t)r * KDIM + c * 8;
    const bf16_t* ag1 = ag0 + (size_t)64 * KDIM;
    const bf16_t* bg0 = Be + (size_t)r * KDIM + c * 8;
    const bf16_t* bg1 = bg0 + (size_t)64 * KDIM;
    const int woff = wave * 512;                 // wave-uniform LDS base (elems)

    const int wm = (wave & 1) * 64, wn = (wave >> 1) * 64;
    const int lr = lane & 15, q = lane >> 4;
    const int sw = (q ^ ((lr >> 1) & 3)) * 8;    // swizzled frag k-slot

    f32x4 acc[4][4] = {};

    // prologue: tile 0 -> buffer 0
    load_lds16(ag0, &As[0][woff]);
    load_lds16(ag1, &As[0][2048 + woff]);
    load_lds16(bg0, &Bs[0][woff]);
    load_lds16(bg1, &Bs[0][2048 + woff]);

    int p = 0;
    for (int k0 = 0; k0 < KLEN; k0 += BK, p ^= 1) {
        const bool more = (k0 + BK < KLEN);
        if (more) {
            const int kn = k0 + BK;
            load_lds16(ag0 + kn, &As[p ^ 1][woff]);
            load_lds16(ag1 + kn, &As[p ^ 1][2048 + woff]);
            load_lds16(bg0 + kn, &Bs[p ^ 1][woff]);
            load_lds16(bg1 + kn, &Bs[p ^ 1][2048 + woff]);
            asm volatile("s_waitcnt vmcnt(4)" ::: "memory");
        } else {
            asm volatile("s_waitcnt vmcnt(0)" ::: "memory");
        }
        asm volatile("s_barrier" ::: "memory");   // buf p ready on all waves
        bf16x8 af[4], bfr[4];
#pragma unroll
        for (int i = 0; i < 4; i++)
            af[i] = *(const bf16x8*)(&As[p][(wm + i * 16 + lr) * BK + sw]);
#pragma unroll
        for (int j = 0; j < 4; j++)
            bfr[j] = *(const bf16x8*)(&Bs[p][(wn + j * 16 + lr) * BK + sw]);
#pragma unroll
        for (int i = 0; i < 4; i++)
#pragma unroll
            for (int j = 0; j < 4; j++)
                acc[i][j] = __builtin_amdgcn_mfma_f32_16x16x32_bf16(af[i], bfr[j], acc[i][j], 0, 0, 0);
        if (more) {
            asm volatile("s_waitcnt lgkmcnt(0)" ::: "memory");  // reads of buf p done
            asm volatile("s_barrier" ::: "memory");             // before its overwrite
        }
    }

    // C/D layout: col = lane&15, row = (lane>>4)*4 + reg.
    if (IS_G1) {
        bf16_t* Ho = Hout + ((size_t)e * CAP + mblk) * NDIM + nblk;
#pragma unroll
        for (int i = 0; i < 4; i++) {
            const int r0 = wm + i * 16 + q * 4;
#pragma unroll
            for (int reg = 0; reg < 4; reg++) {
                bf16_t* row = Ho + (size_t)(r0 + reg) * NDIM;
#pragma unroll
                for (int j = 0; j < 4; j++)
                    row[wn + j * 16 + lr] = (bf16_t)fmaxf(acc[i][j][reg], 0.f);
            }
        }
    } else {
#pragma unroll
        for (int i = 0; i < 4; i++) {
            const int r0 = mblk + wm + i * 16 + q * 4;
#pragma unroll
            for (int reg = 0; reg < 4; reg++) {
                const int row = r0 + reg;
                const int tok = list[e * CAP + row];
                const float wgt = wsel[e * CAP + row];
                if (tok >= 0) {
                    float* orow = out + (size_t)tok * NDIM + nblk;
#pragma unroll
                    for (int j = 0; j < 4; j++)
                        atomicAdd(orow + wn + j * 16 + lr, acc[i][j][reg] * wgt);
                }
            }
        }
    }
}

// ---------------- Fallback GEMM (fused fp32->bf16 B staging, small ws) -----
template<int KDIM, int NDIM, bool IS_G1>
__global__ __launch_bounds__(256) void ffn_gemm_fused(
    const bf16_t* __restrict__ Ab, const float* __restrict__ Wb,
    bf16_t* __restrict__ Hout, const int* __restrict__ list,
    const float* __restrict__ wsel, float* __restrict__ out)
{
    constexpr int BM = 128, BN = 128, BK = 32;
    __shared__ __align__(16) bf16_t As[BM * BK];
    __shared__ __align__(16) bf16_t Bs[BN * BK];
    const int tid = threadIdx.x, wave = tid >> 6, lane = tid & 63;
    const int e = blockIdx.z, mblk = blockIdx.y * BM, nblk = blockIdx.x * BN;

    const bf16_t* Ae = Ab + ((size_t)e * CAP + mblk) * KDIM;
    const float*  We = Wb + (size_t)e * KDIM * NDIM + nblk;

    const int ar = tid >> 2, ac = (tid & 3) * 8;
    const bf16_t* ag0 = Ae + (size_t)ar * KDIM + ac;
    const bf16_t* ag1 = ag0 + (size_t)64 * KDIM;
    bf16_t* as0 = As + wave * 512;
    bf16_t* as1 = As + 2048 + wave * 512;

    const int bn = tid & 127, bc = (tid >> 7) * 2;
    const float* bg = We + bn;
    bf16_t* bsw0 = Bs + bn * BK + ((bc ^ (bn & 3)) * 8);
    bf16_t* bsw1 = Bs + bn * BK + (((bc + 1) ^ (bn & 3)) * 8);

    const int wm = (wave & 1) * 64, wn = (wave >> 1) * 64;
    const int lr = lane & 15, q = lane >> 4;
    const int swz = q ^ ((wn + lr) & 3);

    f32x4 acc[4][4] = {};

    for (int k0 = 0; k0 < KDIM; k0 += BK) {
        load_lds16(ag0 + k0, as0);
        load_lds16(ag1 + k0, as1);
        const float* bp = bg + (size_t)(k0 + bc * 8) * NDIM;
        float v[16];
#pragma unroll
        for (int j = 0; j < 16; j++) v[j] = bp[(size_t)j * NDIM];
        bf16x8 p0 = pack8(v), p1 = pack8(v + 8);
        *(bf16x8*)bsw0 = p0;
        *(bf16x8*)bsw1 = p1;
        __syncthreads();
        bf16x8 af[4], bfr[4];
#pragma unroll
        for (int i = 0; i < 4; i++)
            af[i] = *(const bf16x8*)(As + (wm + i * 16 + lr) * BK + q * 8);
#pragma unroll
        for (int j = 0; j < 4; j++)
            bfr[j] = *(const bf16x8*)(Bs + (wn + j * 16 + lr) * BK + swz * 8);
#pragma unroll
        for (int i = 0; i < 4; i++)
#pragma unroll
            for (int j = 0; j < 4; j++)
                acc[i][j] = __builtin_amdgcn_mfma_f32_16x16x32_bf16(af[i], bfr[j], acc[i][j], 0, 0, 0);
        __syncthreads();
    }

    if (IS_G1) {
        bf16_t* Ho = Hout + ((size_t)e * CAP + mblk) * NDIM + nblk;
#pragma unroll
        for (int i = 0; i < 4; i++) {
            const int r0 = wm + i * 16 + q * 4;
#pragma unroll
            for (int reg = 0; reg < 4; reg++) {
                bf16_t* row = Ho + (size_t)(r0 + reg) * NDIM;
#pragma unroll
                for (int j = 0; j < 4; j++)
                    row[wn + j * 16 + lr] = (bf16_t)fmaxf(acc[i][j][reg], 0.f);
            }
        }
    } else {
#pragma unroll
        for (int i = 0; i < 4; i++) {
            const int r0 = mblk + wm + i * 16 + q * 4;
#pragma unroll
            for (int reg = 0; reg < 4; reg++) {
                const int row = r0 + reg;
                const int tok = list[e * CAP + row];
                const float wgt = wsel[e * CAP + row];
                if (tok >= 0) {
                    float* orow = out + (size_t)tok * NDIM + nblk;
#pragma unroll
                    for (int j = 0; j < 4; j++)
                        atomicAdd(orow + wn + j * 16 + lr, acc[i][j][reg] * wgt);
                }
            }
        }
    }
}

// ---------------- Launch ---------------------------------------------------
extern "C" void kernel_launch(void* const* d_in, const int* in_sizes, int n_in,
                              void* d_out, int out_size, void* d_ws, size_t ws_size,
                              hipStream_t stream) {
    const float* x  = (const float*)d_in[0];
    const float* rw = (const float*)d_in[1];
    const float* rb = (const float*)d_in[2];
    const float* w1 = (const float*)d_in[3];   // [7][1024][4096] f32
    const float* w2 = (const float*)d_in[4];   // [7][4096][1024] f32
    float* out = (float*)d_out;

    char* ws = (char*)d_ws;
    // ws layout:
    //   routew  @0        262144
    //   list    @262144   28672
    //   wsel    @290816   28672
    //   Abuf    @319488   14680064   (bf16 [7][1024][1024])
    //   Hbuf    @14999552 58720256   (bf16 [7][1024][4096])
    //   W1t/W2t @73719808 58720256   (bf16, W2t aliases W1t after GEMM1)
    float*  routew = (float*)(ws);
    int*    list   = (int*)(ws + 262144);
    float*  wsel   = (float*)(ws + 262144 + 28672);
    bf16_t* Abuf   = (bf16_t*)(ws + 319488);
    bf16_t* Hbuf   = (bf16_t*)(ws + 14999552);
    bf16_t* Wt     = (bf16_t*)(ws + 73719808);

    const size_t NEED = 73719808ull + 58720256ull;   // 132.4 MB

    router_kernel<<<N_TOK / 4, 256, 0, stream>>>(x, rw, rb, routew, out);
    compact_kernel<<<NEXP, 1024, 0, stream>>>(routew, list, wsel);
    gather_kernel<<<NEXP * CAP, 128, 0, stream>>>(x, list, Abuf);

    if (ws_size >= NEED) {
        transpose_cvt<HDIM, IDIM><<<dim3(IDIM / 64, HDIM / 64, NEXP), 256, 0, stream>>>(w1, Wt);
        ffn_gemm_t<HDIM, IDIM, 1, true><<<dim3(IDIM / 128, CAP / 128, NEXP), 256, 0, stream>>>(
            Abuf, Wt, Hbuf, nullptr, nullptr, nullptr);
        transpose_cvt<IDIM, HDIM><<<dim3(HDIM / 64, IDIM / 64, NEXP), 256, 0, stream>>>(w2, Wt);
        ffn_gemm_t<IDIM, HDIM, 2, false><<<dim3(HDIM / 128, CAP / 128, NEXP * 2), 256, 0, stream>>>(
            Hbuf, Wt, nullptr, list, wsel, out);
    } else {
        ffn_gemm_fused<HDIM, IDIM, true><<<dim3(IDIM / 128, CAP / 128, NEXP), 256, 0, stream>>>(
            Abuf, w1, Hbuf, nullptr, nullptr, nullptr);
        ffn_gemm_fused<IDIM, HDIM, false><<<dim3(HDIM / 128, CAP / 128, NEXP), 256, 0, stream>>>(
            Hbuf, w2, nullptr, list, wsel, out);
    }
}